// Round 1
// baseline (183.013 us; speedup 1.0000x reference)
//
#include <hip/hip_runtime.h>
#include <hip/hip_bf16.h>
#include <math.h>

// Problem sizes
#define Bn 4096
#define Dn 128
#define Cn 1000
#define Qn 65536

// ---------------- reductions ----------------
__device__ inline float waveMaxF(float v) {
    for (int o = 32; o; o >>= 1) v = fmaxf(v, __shfl_down(v, o));
    return v;
}
__device__ inline float waveSumF(float v) {
    for (int o = 32; o; o >>= 1) v += __shfl_down(v, o);
    return v;
}

// ---------------- kernel 1: classfy softmax + masked argmax ----------------
__global__ __launch_bounds__(256) void k_cls_softmax_argmax(
    const float* __restrict__ logits, const float* __restrict__ plabel,
    float* __restrict__ out, int* __restrict__ labels)
{
    __shared__ float sh[8];
    __shared__ int   shi[4];
    int row = blockIdx.x, t = threadIdx.x;
    const float* x = logits + (long long)row * Cn;

    float v[4];
    float mx = -INFINITY;
#pragma unroll
    for (int u = 0; u < 4; ++u) {
        int c = t + u * 256;
        v[u] = (c < Cn) ? x[c] : -INFINITY;
        mx = fmaxf(mx, v[u]);
    }
    int lane = t & 63, wid = t >> 6;
    mx = waveMaxF(mx);
    if (lane == 0) sh[wid] = mx;
    __syncthreads();
    if (t == 0) {
        float m = sh[0];
        for (int i = 1; i < 4; ++i) m = fmaxf(m, sh[i]);
        sh[4] = m;
    }
    __syncthreads();
    mx = sh[4];

    float s = 0.f;
#pragma unroll
    for (int u = 0; u < 4; ++u) {
        int c = t + u * 256;
        v[u] = (c < Cn) ? expf(v[u] - mx) : 0.f;
        s += v[u];
    }
    s = waveSumF(s);
    if (lane == 0) sh[wid] = s;
    __syncthreads();
    if (t == 0) {
        float ss = 0.f;
        for (int i = 0; i < 4; ++i) ss += sh[i];
        sh[5] = ss;
    }
    __syncthreads();
    s = sh[5];

    float bv = -INFINITY; int bi = Cn;
#pragma unroll
    for (int u = 0; u < 4; ++u) {
        int c = t + u * 256;
        if (c < Cn) {
            float o = v[u] / s;
            out[(long long)row * Cn + c] = o;
            float pr = o * plabel[(long long)row * Cn + c];
            if (pr > bv || (pr == bv && c < bi)) { bv = pr; bi = c; }
        }
    }
    for (int o = 32; o; o >>= 1) {
        float ov = __shfl_down(bv, o);
        int   oi = __shfl_down(bi, o);
        if (ov > bv || (ov == bv && oi < bi)) { bv = ov; bi = oi; }
    }
    __syncthreads();
    if (lane == 0) { sh[wid] = bv; shi[wid] = bi; }
    __syncthreads();
    if (t == 0) {
        float fb = sh[0]; int fi = shi[0];
        for (int i = 1; i < 4; ++i)
            if (sh[i] > fb || (sh[i] == fb && shi[i] < fi)) { fb = sh[i]; fi = shi[i]; }
        labels[row] = fi;
    }
}

// ---------------- kernel 2: logits = q @ proto^T (fp32 vector GEMM) ----------------
// 64x64 output tile per block, K staged in LDS with +1 pad.
__global__ __launch_bounds__(256) void k_gemm(
    const float* __restrict__ q, const float* __restrict__ proto,
    float* __restrict__ outL)
{
    __shared__ float As[64][65];
    __shared__ float Bs[64][65];
    int tx = threadIdx.x & 15, ty = threadIdx.x >> 4;
    int row0 = blockIdx.y * 64;
    int col0 = blockIdx.x * 64;
    float acc[4][4] = {};

    for (int kc = 0; kc < 128; kc += 64) {
        __syncthreads();
#pragma unroll
        for (int li = 0; li < 4; ++li) {
            int flat = li * 256 + threadIdx.x;   // 0..1023
            int r  = flat >> 4;                  // 0..63
            int kq = flat & 15;                  // 0..15
            float4 a4 = *(const float4*)(q + (long long)(row0 + r) * Dn + kc + kq * 4);
            As[r][kq * 4 + 0] = a4.x; As[r][kq * 4 + 1] = a4.y;
            As[r][kq * 4 + 2] = a4.z; As[r][kq * 4 + 3] = a4.w;
            int pr = col0 + r;
            float4 b4 = make_float4(0.f, 0.f, 0.f, 0.f);
            if (pr < Cn) b4 = *(const float4*)(proto + (long long)pr * Dn + kc + kq * 4);
            Bs[r][kq * 4 + 0] = b4.x; Bs[r][kq * 4 + 1] = b4.y;
            Bs[r][kq * 4 + 2] = b4.z; Bs[r][kq * 4 + 3] = b4.w;
        }
        __syncthreads();
#pragma unroll 8
        for (int k = 0; k < 64; ++k) {
            float a0 = As[ty * 4 + 0][k], a1 = As[ty * 4 + 1][k];
            float a2 = As[ty * 4 + 2][k], a3 = As[ty * 4 + 3][k];
            float b0 = Bs[tx * 4 + 0][k], b1 = Bs[tx * 4 + 1][k];
            float b2 = Bs[tx * 4 + 2][k], b3 = Bs[tx * 4 + 3][k];
            acc[0][0] += a0 * b0; acc[0][1] += a0 * b1; acc[0][2] += a0 * b2; acc[0][3] += a0 * b3;
            acc[1][0] += a1 * b0; acc[1][1] += a1 * b1; acc[1][2] += a1 * b2; acc[1][3] += a1 * b3;
            acc[2][0] += a2 * b0; acc[2][1] += a2 * b1; acc[2][2] += a2 * b2; acc[2][3] += a2 * b3;
            acc[3][0] += a3 * b0; acc[3][1] += a3 * b1; acc[3][2] += a3 * b2; acc[3][3] += a3 * b3;
        }
    }
#pragma unroll
    for (int i = 0; i < 4; ++i) {
        int r = row0 + ty * 4 + i;
#pragma unroll
        for (int j = 0; j < 4; ++j) {
            int c = col0 + tx * 4 + j;
            if (c < Cn) outL[(long long)r * Cn + c] = acc[i][j];
        }
    }
}

// ---------------- kernel 3: in-place row softmax over [4096][1000] ----------------
__global__ __launch_bounds__(256) void k_softmax_inplace(float* __restrict__ buf)
{
    __shared__ float sh[8];
    int row = blockIdx.x, t = threadIdx.x;
    float* x = buf + (long long)row * Cn;

    float v[4];
    float mx = -INFINITY;
#pragma unroll
    for (int u = 0; u < 4; ++u) {
        int c = t + u * 256;
        v[u] = (c < Cn) ? x[c] : -INFINITY;
        mx = fmaxf(mx, v[u]);
    }
    int lane = t & 63, wid = t >> 6;
    mx = waveMaxF(mx);
    if (lane == 0) sh[wid] = mx;
    __syncthreads();
    if (t == 0) {
        float m = sh[0];
        for (int i = 1; i < 4; ++i) m = fmaxf(m, sh[i]);
        sh[4] = m;
    }
    __syncthreads();
    mx = sh[4];

    float s = 0.f;
#pragma unroll
    for (int u = 0; u < 4; ++u) {
        int c = t + u * 256;
        v[u] = (c < Cn) ? expf(v[u] - mx) : 0.f;
        s += v[u];
    }
    s = waveSumF(s);
    if (lane == 0) sh[wid] = s;
    __syncthreads();
    if (t == 0) {
        float ss = 0.f;
        for (int i = 0; i < 4; ++i) ss += sh[i];
        sh[5] = ss;
    }
    __syncthreads();
    s = sh[5];
#pragma unroll
    for (int u = 0; u < 4; ++u) {
        int c = t + u * 256;
        if (c < Cn) x[c] = v[u] / s;
    }
}

// ---------------- kernel 4: per-sample rank/count -> weights, per-class counts ----------------
__global__ __launch_bounds__(256) void k_rank(
    const int* __restrict__ labels, float* __restrict__ w, int* __restrict__ counts)
{
    __shared__ int sl[256];
    int i = blockIdx.x * 256 + threadIdx.x;   // 0..4095
    int li = labels[i];
    int cnt = 0, rank = 0;
    for (int j0 = 0; j0 < Bn; j0 += 256) {
        __syncthreads();
        sl[threadIdx.x] = labels[j0 + threadIdx.x];
        __syncthreads();
#pragma unroll 8
        for (int jj = 0; jj < 256; ++jj) {
            int lj = sl[jj];
            int j = j0 + jj;
            if (lj == li) {
                cnt += 1;
                if (j < i) rank += 1;
            }
        }
    }
    w[i] = 0.01f * powf(0.99f, (float)(cnt - 1 - rank));
    if (rank == 0) counts[li] = cnt;   // first sample of each class writes (counts pre-zeroed)
}

// ---------------- kernel 5: weighted scatter-add into [C][D] ----------------
__global__ __launch_bounds__(128) void k_scatter(
    const float* __restrict__ q, const int* __restrict__ labels,
    const float* __restrict__ w, float* __restrict__ scat)
{
    int i = blockIdx.x;        // sample
    int d = threadIdx.x;       // dim
    int l = labels[i];
    float wv = w[i];
    atomicAdd(&scat[(long long)l * Dn + d], wv * q[(long long)i * Dn + d]);
}

// ---------------- kernel 6: prototype decay + scatter + L2 norm ----------------
__global__ __launch_bounds__(128) void k_proto(
    const float* __restrict__ proto, const float* __restrict__ scat,
    const int* __restrict__ counts, float* __restrict__ outp)
{
    __shared__ float sh[2];
    int c = blockIdx.x, d = threadIdx.x;
    float decay = powf(0.99f, (float)counts[c]);
    float v = proto[(long long)c * Dn + d] * decay + scat[(long long)c * Dn + d];
    float ss = v * v;
    ss = waveSumF(ss);
    int lane = d & 63, wid = d >> 6;
    if (lane == 0) sh[wid] = ss;
    __syncthreads();
    float n = sqrtf(sh[0] + sh[1]);
    outp[(long long)c * Dn + d] = v / fmaxf(n, 1e-12f);
}

// ---------------- kernel 7: cont_features = concat(q, k, queue) ----------------
__global__ void k_feat(const float* __restrict__ q, const float* __restrict__ kk,
                       const float* __restrict__ queue, float* __restrict__ out)
{
    const long long QD = (long long)Bn * Dn;           // 524288
    const long long n4 = (2 * QD + (long long)Qn * Dn) / 4;  // 2359296
    long long stride = (long long)gridDim.x * blockDim.x;
    for (long long i = (long long)blockIdx.x * blockDim.x + threadIdx.x; i < n4; i += stride) {
        long long off = i * 4;
        float4 v;
        if (off < QD)          v = *(const float4*)(q + off);
        else if (off < 2 * QD) v = *(const float4*)(kk + off - QD);
        else                   v = *(const float4*)(queue + off - 2 * QD);
        *(float4*)(out + off) = v;
    }
}

// ---------------- kernel 8: new_queue = queue with rows [p, p+B) <- k ----------------
__global__ void k_newq(const float* __restrict__ kk, const float* __restrict__ queue,
                       const int* __restrict__ ptrp, float* __restrict__ out)
{
    int p = *ptrp;
    if (p < 0) p = 0;
    if (p > Qn - Bn) p = Qn - Bn;   // dynamic_update_slice clamp
    const long long n4 = (long long)Qn * Dn / 4;
    long long stride = (long long)gridDim.x * blockDim.x;
    for (long long i = (long long)blockIdx.x * blockDim.x + threadIdx.x; i < n4; i += stride) {
        long long off = i * 4;
        int row = (int)(off >> 7);
        int col = (int)(off & 127);
        unsigned rr = (unsigned)(row - p);
        float4 v;
        if (rr < (unsigned)Bn) v = *(const float4*)(kk + (long long)rr * Dn + col);
        else                   v = *(const float4*)(queue + off);
        *(float4*)(out + off) = v;
    }
}

// ---------------- kernel 9: cont_labels, new_queue_pseudo, new_ptr ----------------
__global__ void k_labels(const int* __restrict__ lbl, const float* __restrict__ qps,
                         const int* __restrict__ ptrp,
                         float* __restrict__ out_lab, float* __restrict__ out_qps,
                         float* __restrict__ out_ptr)
{
    int i = blockIdx.x * blockDim.x + threadIdx.x;
    const int NL = 2 * Bn + Qn;   // 73728
    int p = *ptrp;
    int pc = p < 0 ? 0 : (p > Qn - Bn ? Qn - Bn : p);
    if (i < NL) {
        float v;
        if (i < Bn)          v = (float)lbl[i];
        else if (i < 2 * Bn) v = (float)lbl[i - Bn];
        else                 v = qps[i - 2 * Bn];
        out_lab[i] = v;
    }
    int j = i - NL;
    if (j >= 0 && j < Qn) {
        unsigned rr = (unsigned)(j - pc);
        out_qps[j] = (rr < (unsigned)Bn) ? (float)lbl[rr] : qps[j];
    }
    if (i == NL + Qn) out_ptr[0] = (float)((p + Bn) % Qn);
}

// ---------------- host ----------------
extern "C" void kernel_launch(void* const* d_in, const int* in_sizes, int n_in,
                              void* d_out, int out_size, void* d_ws, size_t ws_size,
                              hipStream_t stream)
{
    const float* q     = (const float*)d_in[0];
    const float* kk    = (const float*)d_in[1];
    const float* cl    = (const float*)d_in[2];
    const float* plab  = (const float*)d_in[3];
    const float* proto = (const float*)d_in[4];
    const float* queue = (const float*)d_in[5];
    const float* qps   = (const float*)d_in[6];
    const int*   ptrp  = (const int*)d_in[7];

    float* out = (float*)d_out;
    // output layout (flat float offsets, return order)
    const long long O_CLU  = 4096000;     // cluster_out
    const long long O_FEAT = 8192000;     // cont_features
    const long long O_LAB  = 17629184;    // cont_labels
    const long long O_PROT = 17702912;    // new_prototypes
    const long long O_QUE  = 17830912;    // new_queue
    const long long O_QPS  = 26219520;    // new_queue_pseudo
    const long long O_PTR  = 26285056;    // new_ptr

    char* ws = (char*)d_ws;
    int*   lbl    = (int*)(ws + 0);          // [4096]
    float* w      = (float*)(ws + 16384);    // [4096]
    int*   counts = (int*)(ws + 32768);      // [1024]
    float* scat   = (float*)(ws + 36864);    // [128000]

    // zero counts + scatter (contiguous)
    hipMemsetAsync(ws + 32768, 0, 4096 + 512000, stream);

    k_cls_softmax_argmax<<<Bn, 256, 0, stream>>>(cl, plab, out, lbl);
    k_gemm<<<dim3(16, 64), 256, 0, stream>>>(q, proto, out + O_CLU);
    k_softmax_inplace<<<Bn, 256, 0, stream>>>(out + O_CLU);
    k_rank<<<Bn / 256, 256, 0, stream>>>(lbl, w, counts);
    k_scatter<<<Bn, 128, 0, stream>>>(q, lbl, w, scat);
    k_proto<<<Cn, 128, 0, stream>>>(proto, scat, counts, out + O_PROT);
    k_feat<<<2048, 256, 0, stream>>>(q, kk, queue, out + O_FEAT);
    k_newq<<<2048, 256, 0, stream>>>(kk, queue, ptrp, out + O_QUE);
    k_labels<<<(2 * Bn + 2 * Qn + 1 + 255) / 256, 256, 0, stream>>>(
        lbl, qps, ptrp, out + O_LAB, out + O_QPS, out + O_PTR);
}

// Round 2
// 89.064 us; speedup vs baseline: 2.0549x; 2.0549x over previous
//
#include <hip/hip_runtime.h>
#include <hip/hip_bf16.h>
#include <math.h>

// Problem sizes
#define Bn 4096
#define Dn 128
#define Cn 1000
#define Qn 65536

// ---------------- reductions ----------------
__device__ inline float waveMaxF(float v) {
    for (int o = 32; o; o >>= 1) v = fmaxf(v, __shfl_down(v, o));
    return v;
}
__device__ inline float waveSumF(float v) {
    for (int o = 32; o; o >>= 1) v += __shfl_down(v, o);
    return v;
}

// ---------------- kernel 1: classfy softmax + masked argmax ----------------
__global__ __launch_bounds__(256) void k_cls_softmax_argmax(
    const float* __restrict__ logits, const float* __restrict__ plabel,
    float* __restrict__ out, int* __restrict__ labels)
{
    __shared__ float sh[8];
    __shared__ int   shi[4];
    int row = blockIdx.x, t = threadIdx.x;
    const float* x = logits + (long long)row * Cn;

    float v[4];
    float mx = -INFINITY;
#pragma unroll
    for (int u = 0; u < 4; ++u) {
        int c = t + u * 256;
        v[u] = (c < Cn) ? x[c] : -INFINITY;
        mx = fmaxf(mx, v[u]);
    }
    int lane = t & 63, wid = t >> 6;
    mx = waveMaxF(mx);
    if (lane == 0) sh[wid] = mx;
    __syncthreads();
    if (t == 0) {
        float m = sh[0];
        for (int i = 1; i < 4; ++i) m = fmaxf(m, sh[i]);
        sh[4] = m;
    }
    __syncthreads();
    mx = sh[4];

    float s = 0.f;
#pragma unroll
    for (int u = 0; u < 4; ++u) {
        int c = t + u * 256;
        v[u] = (c < Cn) ? expf(v[u] - mx) : 0.f;
        s += v[u];
    }
    s = waveSumF(s);
    if (lane == 0) sh[wid] = s;
    __syncthreads();
    if (t == 0) {
        float ss = 0.f;
        for (int i = 0; i < 4; ++i) ss += sh[i];
        sh[5] = ss;
    }
    __syncthreads();
    s = sh[5];

    float bv = -INFINITY; int bi = Cn;
#pragma unroll
    for (int u = 0; u < 4; ++u) {
        int c = t + u * 256;
        if (c < Cn) {
            float o = v[u] / s;
            out[(long long)row * Cn + c] = o;
            float pr = o * plabel[(long long)row * Cn + c];
            if (pr > bv || (pr == bv && c < bi)) { bv = pr; bi = c; }
        }
    }
    for (int o = 32; o; o >>= 1) {
        float ov = __shfl_down(bv, o);
        int   oi = __shfl_down(bi, o);
        if (ov > bv || (ov == bv && oi < bi)) { bv = ov; bi = oi; }
    }
    __syncthreads();
    if (lane == 0) { sh[wid] = bv; shi[wid] = bi; }
    __syncthreads();
    if (t == 0) {
        float fb = sh[0]; int fi = shi[0];
        for (int i = 1; i < 4; ++i)
            if (sh[i] > fb || (sh[i] == fb && shi[i] < fi)) { fb = sh[i]; fi = shi[i]; }
        labels[row] = fi;
    }
}

// ---------------- kernel 2: logits = q @ proto^T (fp32 vector GEMM) ----------------
__global__ __launch_bounds__(256) void k_gemm(
    const float* __restrict__ q, const float* __restrict__ proto,
    float* __restrict__ outL)
{
    __shared__ float As[64][65];
    __shared__ float Bs[64][65];
    int tx = threadIdx.x & 15, ty = threadIdx.x >> 4;
    int row0 = blockIdx.y * 64;
    int col0 = blockIdx.x * 64;
    float acc[4][4] = {};

    for (int kc = 0; kc < 128; kc += 64) {
        __syncthreads();
#pragma unroll
        for (int li = 0; li < 4; ++li) {
            int flat = li * 256 + threadIdx.x;   // 0..1023
            int r  = flat >> 4;                  // 0..63
            int kq = flat & 15;                  // 0..15
            float4 a4 = *(const float4*)(q + (long long)(row0 + r) * Dn + kc + kq * 4);
            As[r][kq * 4 + 0] = a4.x; As[r][kq * 4 + 1] = a4.y;
            As[r][kq * 4 + 2] = a4.z; As[r][kq * 4 + 3] = a4.w;
            int pr = col0 + r;
            float4 b4 = make_float4(0.f, 0.f, 0.f, 0.f);
            if (pr < Cn) b4 = *(const float4*)(proto + (long long)pr * Dn + kc + kq * 4);
            Bs[r][kq * 4 + 0] = b4.x; Bs[r][kq * 4 + 1] = b4.y;
            Bs[r][kq * 4 + 2] = b4.z; Bs[r][kq * 4 + 3] = b4.w;
        }
        __syncthreads();
#pragma unroll 8
        for (int k = 0; k < 64; ++k) {
            float a0 = As[ty * 4 + 0][k], a1 = As[ty * 4 + 1][k];
            float a2 = As[ty * 4 + 2][k], a3 = As[ty * 4 + 3][k];
            float b0 = Bs[tx * 4 + 0][k], b1 = Bs[tx * 4 + 1][k];
            float b2 = Bs[tx * 4 + 2][k], b3 = Bs[tx * 4 + 3][k];
            acc[0][0] += a0 * b0; acc[0][1] += a0 * b1; acc[0][2] += a0 * b2; acc[0][3] += a0 * b3;
            acc[1][0] += a1 * b0; acc[1][1] += a1 * b1; acc[1][2] += a1 * b2; acc[1][3] += a1 * b3;
            acc[2][0] += a2 * b0; acc[2][1] += a2 * b1; acc[2][2] += a2 * b2; acc[2][3] += a2 * b3;
            acc[3][0] += a3 * b0; acc[3][1] += a3 * b1; acc[3][2] += a3 * b2; acc[3][3] += a3 * b3;
        }
    }
#pragma unroll
    for (int i = 0; i < 4; ++i) {
        int r = row0 + ty * 4 + i;
#pragma unroll
        for (int j = 0; j < 4; ++j) {
            int c = col0 + tx * 4 + j;
            if (c < Cn) outL[(long long)r * Cn + c] = acc[i][j];
        }
    }
}

// ---------------- kernel 3: in-place row softmax over [4096][1000] ----------------
__global__ __launch_bounds__(256) void k_softmax_inplace(float* __restrict__ buf)
{
    __shared__ float sh[8];
    int row = blockIdx.x, t = threadIdx.x;
    float* x = buf + (long long)row * Cn;

    float v[4];
    float mx = -INFINITY;
#pragma unroll
    for (int u = 0; u < 4; ++u) {
        int c = t + u * 256;
        v[u] = (c < Cn) ? x[c] : -INFINITY;
        mx = fmaxf(mx, v[u]);
    }
    int lane = t & 63, wid = t >> 6;
    mx = waveMaxF(mx);
    if (lane == 0) sh[wid] = mx;
    __syncthreads();
    if (t == 0) {
        float m = sh[0];
        for (int i = 1; i < 4; ++i) m = fmaxf(m, sh[i]);
        sh[4] = m;
    }
    __syncthreads();
    mx = sh[4];

    float s = 0.f;
#pragma unroll
    for (int u = 0; u < 4; ++u) {
        int c = t + u * 256;
        v[u] = (c < Cn) ? expf(v[u] - mx) : 0.f;
        s += v[u];
    }
    s = waveSumF(s);
    if (lane == 0) sh[wid] = s;
    __syncthreads();
    if (t == 0) {
        float ss = 0.f;
        for (int i = 0; i < 4; ++i) ss += sh[i];
        sh[5] = ss;
    }
    __syncthreads();
    s = sh[5];
#pragma unroll
    for (int u = 0; u < 4; ++u) {
        int c = t + u * 256;
        if (c < Cn) x[c] = v[u] / s;
    }
}

// ---------------- kernel 4: rank/count — ONE WAVE PER SAMPLE ----------------
// 1024 blocks x 256 threads (4 waves). Block stages all 4096 labels in LDS;
// wave w owns sample i = blockIdx.x*4 + w; lane l scans j = jj*64 + l
// (consecutive lanes -> consecutive LDS words -> 2-way aliasing, free).
__global__ __launch_bounds__(256) void k_rank(
    const int* __restrict__ labels, float* __restrict__ w, int* __restrict__ counts)
{
    __shared__ int sl[Bn];
    int t = threadIdx.x;
#pragma unroll
    for (int u = 0; u < Bn / (256 * 4); ++u) {
        int4 v4 = *(const int4*)(labels + (u * 256 + t) * 4);
        *(int4*)(sl + (u * 256 + t) * 4) = v4;
    }
    __syncthreads();

    int lane = t & 63, wid = t >> 6;
    int i = blockIdx.x * 4 + wid;
    int li = sl[i];
    int cnt = 0, rank = 0;
#pragma unroll 8
    for (int jj = 0; jj < Bn / 64; ++jj) {
        int j = jj * 64 + lane;
        int match = (sl[j] == li) ? 1 : 0;
        cnt += match;
        rank += (j < i) ? match : 0;
    }
    for (int o = 32; o; o >>= 1) {
        cnt  += __shfl_down(cnt, o);
        rank += __shfl_down(rank, o);
    }
    if (lane == 0) {
        w[i] = 0.01f * powf(0.99f, (float)(cnt - 1 - rank));
        if (rank == 0) counts[li] = cnt;   // exactly one writer per class
    }
}

// ---------------- kernel 5: weighted scatter-add into [C][D] ----------------
__global__ __launch_bounds__(128) void k_scatter(
    const float* __restrict__ q, const int* __restrict__ labels,
    const float* __restrict__ w, float* __restrict__ scat)
{
    int i = blockIdx.x;        // sample
    int d = threadIdx.x;       // dim
    int l = labels[i];
    float wv = w[i];
    atomicAdd(&scat[(long long)l * Dn + d], wv * q[(long long)i * Dn + d]);
}

// ---------------- kernel 6: prototype decay + scatter + L2 norm ----------------
__global__ __launch_bounds__(128) void k_proto(
    const float* __restrict__ proto, const float* __restrict__ scat,
    const int* __restrict__ counts, float* __restrict__ outp)
{
    __shared__ float sh[2];
    int c = blockIdx.x, d = threadIdx.x;
    float decay = powf(0.99f, (float)counts[c]);
    float v = proto[(long long)c * Dn + d] * decay + scat[(long long)c * Dn + d];
    float ss = v * v;
    ss = waveSumF(ss);
    int lane = d & 63, wid = d >> 6;
    if (lane == 0) sh[wid] = ss;
    __syncthreads();
    float n = sqrtf(sh[0] + sh[1]);
    outp[(long long)c * Dn + d] = v / fmaxf(n, 1e-12f);
}

// ---------------- kernel 7: fused copies ----------------
// cont_features = concat(q, k, queue)  AND  new_queue (queue read ONCE)
__global__ void k_copy(const float* __restrict__ q, const float* __restrict__ kk,
                       const float* __restrict__ queue, const int* __restrict__ ptrp,
                       float* __restrict__ out_feat, float* __restrict__ out_queue)
{
    int p = *ptrp;
    if (p < 0) p = 0;
    if (p > Qn - Bn) p = Qn - Bn;   // dynamic_update_slice clamp
    const long long QD = (long long)Bn * Dn;                  // 524288
    const long long n4 = (2 * QD + (long long)Qn * Dn) / 4;   // 2359296
    long long stride = (long long)gridDim.x * blockDim.x;
    for (long long i = (long long)blockIdx.x * blockDim.x + threadIdx.x; i < n4; i += stride) {
        long long off = i * 4;
        if (off < QD) {
            *(float4*)(out_feat + off) = *(const float4*)(q + off);
        } else if (off < 2 * QD) {
            *(float4*)(out_feat + off) = *(const float4*)(kk + off - QD);
        } else {
            long long qoff = off - 2 * QD;
            float4 v = *(const float4*)(queue + qoff);
            *(float4*)(out_feat + off) = v;
            int row = (int)(qoff >> 7);
            int col = (int)(qoff & 127);
            unsigned rr = (unsigned)(row - p);
            if (rr < (unsigned)Bn) v = *(const float4*)(kk + (long long)rr * Dn + col);
            *(float4*)(out_queue + qoff) = v;
        }
    }
}

// ---------------- kernel 8: cont_labels, new_queue_pseudo, new_ptr ----------------
__global__ void k_labels(const int* __restrict__ lbl, const float* __restrict__ qps,
                         const int* __restrict__ ptrp,
                         float* __restrict__ out_lab, float* __restrict__ out_qps,
                         float* __restrict__ out_ptr)
{
    int i = blockIdx.x * blockDim.x + threadIdx.x;
    const int NL = 2 * Bn + Qn;   // 73728
    int p = *ptrp;
    int pc = p < 0 ? 0 : (p > Qn - Bn ? Qn - Bn : p);
    if (i < NL) {
        float v;
        if (i < Bn)          v = (float)lbl[i];
        else if (i < 2 * Bn) v = (float)lbl[i - Bn];
        else                 v = qps[i - 2 * Bn];
        out_lab[i] = v;
    }
    int j = i - NL;
    if (j >= 0 && j < Qn) {
        unsigned rr = (unsigned)(j - pc);
        out_qps[j] = (rr < (unsigned)Bn) ? (float)lbl[rr] : qps[j];
    }
    if (i == NL + Qn) out_ptr[0] = (float)((p + Bn) % Qn);
}

// ---------------- host ----------------
extern "C" void kernel_launch(void* const* d_in, const int* in_sizes, int n_in,
                              void* d_out, int out_size, void* d_ws, size_t ws_size,
                              hipStream_t stream)
{
    const float* q     = (const float*)d_in[0];
    const float* kk    = (const float*)d_in[1];
    const float* cl    = (const float*)d_in[2];
    const float* plab  = (const float*)d_in[3];
    const float* proto = (const float*)d_in[4];
    const float* queue = (const float*)d_in[5];
    const float* qps   = (const float*)d_in[6];
    const int*   ptrp  = (const int*)d_in[7];

    float* out = (float*)d_out;
    // output layout (flat float offsets, return order)
    const long long O_CLU  = 4096000;     // cluster_out
    const long long O_FEAT = 8192000;     // cont_features
    const long long O_LAB  = 17629184;    // cont_labels
    const long long O_PROT = 17702912;    // new_prototypes
    const long long O_QUE  = 17830912;    // new_queue
    const long long O_QPS  = 26219520;    // new_queue_pseudo
    const long long O_PTR  = 26285056;    // new_ptr

    char* ws = (char*)d_ws;
    int*   lbl    = (int*)(ws + 0);          // [4096]
    float* w      = (float*)(ws + 16384);    // [4096]
    int*   counts = (int*)(ws + 32768);      // [1024]
    float* scat   = (float*)(ws + 36864);    // [128000]

    // zero counts + scatter (contiguous)
    hipMemsetAsync(ws + 32768, 0, 4096 + 512000, stream);

    k_cls_softmax_argmax<<<Bn, 256, 0, stream>>>(cl, plab, out, lbl);
    k_gemm<<<dim3(16, 64), 256, 0, stream>>>(q, proto, out + O_CLU);
    k_softmax_inplace<<<Bn, 256, 0, stream>>>(out + O_CLU);
    k_rank<<<Bn / 4, 256, 0, stream>>>(lbl, w, counts);
    k_scatter<<<Bn, 128, 0, stream>>>(q, lbl, w, scat);
    k_proto<<<Cn, 128, 0, stream>>>(proto, scat, counts, out + O_PROT);
    k_copy<<<2048, 256, 0, stream>>>(q, kk, queue, ptrp, out + O_FEAT, out + O_QUE);
    k_labels<<<(2 * Bn + 2 * Qn + 1 + 255) / 256, 256, 0, stream>>>(
        lbl, qps, ptrp, out + O_LAB, out + O_QPS, out + O_PTR);
}

// Round 3
// 76.924 us; speedup vs baseline: 2.3791x; 1.1578x over previous
//
#include <hip/hip_runtime.h>
#include <hip/hip_bf16.h>
#include <math.h>

// Problem sizes
#define Bn 4096
#define Dn 128
#define Cn 1000
#define Qn 65536
#define CPAD 1024   // proto rows padded (zeros) so fragment loads are in-bounds

typedef __attribute__((ext_vector_type(8))) short short8v;  // bf16x8 MFMA frag
typedef __attribute__((ext_vector_type(4))) float f32x4;    // fp32x4 acc frag

// ---------------- reductions ----------------
__device__ inline float waveMaxF(float v) {
    for (int o = 32; o; o >>= 1) v = fmaxf(v, __shfl_down(v, o));
    return v;
}
__device__ inline float waveSumF(float v) {
    for (int o = 32; o; o >>= 1) v += __shfl_down(v, o);
    return v;
}

// ---------------- kernel 1: classfy softmax + masked argmax ----------------
__global__ __launch_bounds__(256) void k_cls_softmax_argmax(
    const float* __restrict__ logits, const float* __restrict__ plabel,
    float* __restrict__ out, int* __restrict__ labels)
{
    __shared__ float sh[8];
    __shared__ int   shi[4];
    int row = blockIdx.x, t = threadIdx.x;
    const float* x = logits + (long long)row * Cn;

    float v[4];
    float mx = -INFINITY;
#pragma unroll
    for (int u = 0; u < 4; ++u) {
        int c = t + u * 256;
        v[u] = (c < Cn) ? x[c] : -INFINITY;
        mx = fmaxf(mx, v[u]);
    }
    int lane = t & 63, wid = t >> 6;
    mx = waveMaxF(mx);
    if (lane == 0) sh[wid] = mx;
    __syncthreads();
    if (t == 0) {
        float m = sh[0];
        for (int i = 1; i < 4; ++i) m = fmaxf(m, sh[i]);
        sh[4] = m;
    }
    __syncthreads();
    mx = sh[4];

    float s = 0.f;
#pragma unroll
    for (int u = 0; u < 4; ++u) {
        int c = t + u * 256;
        v[u] = (c < Cn) ? expf(v[u] - mx) : 0.f;
        s += v[u];
    }
    s = waveSumF(s);
    if (lane == 0) sh[wid] = s;
    __syncthreads();
    if (t == 0) {
        float ss = 0.f;
        for (int i = 0; i < 4; ++i) ss += sh[i];
        sh[5] = ss;
    }
    __syncthreads();
    s = sh[5];

    float bv = -INFINITY; int bi = Cn;
#pragma unroll
    for (int u = 0; u < 4; ++u) {
        int c = t + u * 256;
        if (c < Cn) {
            float o = v[u] / s;
            out[(long long)row * Cn + c] = o;
            float pr = o * plabel[(long long)row * Cn + c];
            if (pr > bv || (pr == bv && c < bi)) { bv = pr; bi = c; }
        }
    }
    for (int o = 32; o; o >>= 1) {
        float ov = __shfl_down(bv, o);
        int   oi = __shfl_down(bi, o);
        if (ov > bv || (ov == bv && oi < bi)) { bv = ov; bi = oi; }
    }
    __syncthreads();
    if (lane == 0) { sh[wid] = bv; shi[wid] = bi; }
    __syncthreads();
    if (t == 0) {
        float fb = sh[0]; int fi = shi[0];
        for (int i = 1; i < 4; ++i)
            if (sh[i] > fb || (sh[i] == fb && shi[i] < fi)) { fb = sh[i]; fi = shi[i]; }
        labels[row] = fi;
    }
}

// ---------------- kernel 2a: fp32 -> bf16 convert (q and padded proto) ----------------
__global__ __launch_bounds__(256) void k_convert(
    const float* __restrict__ q, const float* __restrict__ proto,
    __hip_bfloat16* __restrict__ qb, __hip_bfloat16* __restrict__ pb)
{
    int i = blockIdx.x * 256 + threadIdx.x;
    const int NQ = Bn * Dn;       // 524288
    const int NP = CPAD * Dn;     // 131072 (padded)
    if (i < NQ) qb[i] = __float2bfloat16(q[i]);
    int j = i - NQ;
    if (j >= 0 && j < NP)
        pb[j] = __float2bfloat16(j < Cn * Dn ? proto[j] : 0.f);
}

// ---------------- kernel 2b: logits = qb @ pb^T via MFMA ----------------
// 64x64 block tile, 4 waves in 2x2, each wave a 32x32 tile.
// Fragments read directly from global (qb 1MB + pb 256KB are L2-resident).
// A/B frag: lane holds 8 bf16 of row (lane&15) at k = kc + (lane>>4)*8.
// C/D (m89-verified): col = lane&15, row = (lane>>4)*4 + reg.
__global__ __launch_bounds__(256) void k_gemm_mfma(
    const __hip_bfloat16* __restrict__ qb, const __hip_bfloat16* __restrict__ pb,
    float* __restrict__ outL)
{
    int wid = threadIdx.x >> 6, lane = threadIdx.x & 63;
    int wr = wid >> 1, wc = wid & 1;
    int r0 = blockIdx.y * 64 + wr * 32;
    int c0 = blockIdx.x * 64 + wc * 32;
    int la = lane & 15, lk = lane >> 4;

    f32x4 acc[2][2] = {};
#pragma unroll
    for (int kc = 0; kc < Dn; kc += 32) {
        short8v a[2], b[2];
#pragma unroll
        for (int t = 0; t < 2; ++t) {
            a[t] = *(const short8v*)((const short*)qb + (long long)(r0 + t * 16 + la) * Dn + kc + lk * 8);
            b[t] = *(const short8v*)((const short*)pb + (long long)(c0 + t * 16 + la) * Dn + kc + lk * 8);
        }
#pragma unroll
        for (int i = 0; i < 2; ++i)
#pragma unroll
            for (int j = 0; j < 2; ++j)
                acc[i][j] = __builtin_amdgcn_mfma_f32_16x16x32_bf16(a[i], b[j], acc[i][j], 0, 0, 0);
    }
#pragma unroll
    for (int i = 0; i < 2; ++i)
#pragma unroll
        for (int j = 0; j < 2; ++j) {
            int col = c0 + j * 16 + la;
            if (col < Cn) {
                int rowb = r0 + i * 16 + lk * 4;
#pragma unroll
                for (int rg = 0; rg < 4; ++rg)
                    outL[(long long)(rowb + rg) * Cn + col] = acc[i][j][rg];
            }
        }
}

// ---------------- kernel 3: in-place row softmax over [4096][1000] ----------------
__global__ __launch_bounds__(256) void k_softmax_inplace(float* __restrict__ buf)
{
    __shared__ float sh[8];
    int row = blockIdx.x, t = threadIdx.x;
    float* x = buf + (long long)row * Cn;

    float v[4];
    float mx = -INFINITY;
#pragma unroll
    for (int u = 0; u < 4; ++u) {
        int c = t + u * 256;
        v[u] = (c < Cn) ? x[c] : -INFINITY;
        mx = fmaxf(mx, v[u]);
    }
    int lane = t & 63, wid = t >> 6;
    mx = waveMaxF(mx);
    if (lane == 0) sh[wid] = mx;
    __syncthreads();
    if (t == 0) {
        float m = sh[0];
        for (int i = 1; i < 4; ++i) m = fmaxf(m, sh[i]);
        sh[4] = m;
    }
    __syncthreads();
    mx = sh[4];

    float s = 0.f;
#pragma unroll
    for (int u = 0; u < 4; ++u) {
        int c = t + u * 256;
        v[u] = (c < Cn) ? expf(v[u] - mx) : 0.f;
        s += v[u];
    }
    s = waveSumF(s);
    if (lane == 0) sh[wid] = s;
    __syncthreads();
    if (t == 0) {
        float ss = 0.f;
        for (int i = 0; i < 4; ++i) ss += sh[i];
        sh[5] = ss;
    }
    __syncthreads();
    s = sh[5];
#pragma unroll
    for (int u = 0; u < 4; ++u) {
        int c = t + u * 256;
        if (c < Cn) x[c] = v[u] / s;
    }
}

// ---------------- kernel 4: rank/count — one wave per sample ----------------
__global__ __launch_bounds__(256) void k_rank(
    const int* __restrict__ labels, float* __restrict__ w, int* __restrict__ counts)
{
    __shared__ int sl[Bn];
    int t = threadIdx.x;
#pragma unroll
    for (int u = 0; u < Bn / (256 * 4); ++u) {
        int4 v4 = *(const int4*)(labels + (u * 256 + t) * 4);
        *(int4*)(sl + (u * 256 + t) * 4) = v4;
    }
    __syncthreads();

    int lane = t & 63, wid = t >> 6;
    int i = blockIdx.x * 4 + wid;
    int li = sl[i];
    int cnt = 0, rank = 0;
#pragma unroll 8
    for (int jj = 0; jj < Bn / 64; ++jj) {
        int j = jj * 64 + lane;
        int match = (sl[j] == li) ? 1 : 0;
        cnt += match;
        rank += (j < i) ? match : 0;
    }
    for (int o = 32; o; o >>= 1) {
        cnt  += __shfl_down(cnt, o);
        rank += __shfl_down(rank, o);
    }
    if (lane == 0) {
        w[i] = 0.01f * powf(0.99f, (float)(cnt - 1 - rank));
        if (rank == 0) counts[li] = cnt;   // exactly one writer per class
    }
}

// ---------------- kernel 5: weighted scatter-add into [C][D] ----------------
__global__ __launch_bounds__(128) void k_scatter(
    const float* __restrict__ q, const int* __restrict__ labels,
    const float* __restrict__ w, float* __restrict__ scat)
{
    int i = blockIdx.x;        // sample
    int d = threadIdx.x;       // dim
    int l = labels[i];
    float wv = w[i];
    atomicAdd(&scat[(long long)l * Dn + d], wv * q[(long long)i * Dn + d]);
}

// ---------------- kernel 6: prototype decay + scatter + L2 norm ----------------
__global__ __launch_bounds__(128) void k_proto(
    const float* __restrict__ proto, const float* __restrict__ scat,
    const int* __restrict__ counts, float* __restrict__ outp)
{
    __shared__ float sh[2];
    int c = blockIdx.x, d = threadIdx.x;
    float decay = powf(0.99f, (float)counts[c]);
    float v = proto[(long long)c * Dn + d] * decay + scat[(long long)c * Dn + d];
    float ss = v * v;
    ss = waveSumF(ss);
    int lane = d & 63, wid = d >> 6;
    if (lane == 0) sh[wid] = ss;
    __syncthreads();
    float n = sqrtf(sh[0] + sh[1]);
    outp[(long long)c * Dn + d] = v / fmaxf(n, 1e-12f);
}

// ---------------- kernel 7: fused copies (queue read once) ----------------
__global__ void k_copy(const float* __restrict__ q, const float* __restrict__ kk,
                       const float* __restrict__ queue, const int* __restrict__ ptrp,
                       float* __restrict__ out_feat, float* __restrict__ out_queue)
{
    int p = *ptrp;
    if (p < 0) p = 0;
    if (p > Qn - Bn) p = Qn - Bn;   // dynamic_update_slice clamp
    const long long QD = (long long)Bn * Dn;                  // 524288
    const long long n4 = (2 * QD + (long long)Qn * Dn) / 4;   // 2359296
    long long stride = (long long)gridDim.x * blockDim.x;
    for (long long i = (long long)blockIdx.x * blockDim.x + threadIdx.x; i < n4; i += stride) {
        long long off = i * 4;
        if (off < QD) {
            *(float4*)(out_feat + off) = *(const float4*)(q + off);
        } else if (off < 2 * QD) {
            *(float4*)(out_feat + off) = *(const float4*)(kk + off - QD);
        } else {
            long long qoff = off - 2 * QD;
            float4 v = *(const float4*)(queue + qoff);
            *(float4*)(out_feat + off) = v;
            int row = (int)(qoff >> 7);
            int col = (int)(qoff & 127);
            unsigned rr = (unsigned)(row - p);
            if (rr < (unsigned)Bn) v = *(const float4*)(kk + (long long)rr * Dn + col);
            *(float4*)(out_queue + qoff) = v;
        }
    }
}

// ---------------- kernel 8: cont_labels, new_queue_pseudo, new_ptr ----------------
__global__ void k_labels(const int* __restrict__ lbl, const float* __restrict__ qps,
                         const int* __restrict__ ptrp,
                         float* __restrict__ out_lab, float* __restrict__ out_qps,
                         float* __restrict__ out_ptr)
{
    int i = blockIdx.x * blockDim.x + threadIdx.x;
    const int NL = 2 * Bn + Qn;   // 73728
    int p = *ptrp;
    int pc = p < 0 ? 0 : (p > Qn - Bn ? Qn - Bn : p);
    if (i < NL) {
        float v;
        if (i < Bn)          v = (float)lbl[i];
        else if (i < 2 * Bn) v = (float)lbl[i - Bn];
        else                 v = qps[i - 2 * Bn];
        out_lab[i] = v;
    }
    int j = i - NL;
    if (j >= 0 && j < Qn) {
        unsigned rr = (unsigned)(j - pc);
        out_qps[j] = (rr < (unsigned)Bn) ? (float)lbl[rr] : qps[j];
    }
    if (i == NL + Qn) out_ptr[0] = (float)((p + Bn) % Qn);
}

// ---------------- host ----------------
extern "C" void kernel_launch(void* const* d_in, const int* in_sizes, int n_in,
                              void* d_out, int out_size, void* d_ws, size_t ws_size,
                              hipStream_t stream)
{
    const float* q     = (const float*)d_in[0];
    const float* kk    = (const float*)d_in[1];
    const float* cl    = (const float*)d_in[2];
    const float* plab  = (const float*)d_in[3];
    const float* proto = (const float*)d_in[4];
    const float* queue = (const float*)d_in[5];
    const float* qps   = (const float*)d_in[6];
    const int*   ptrp  = (const int*)d_in[7];

    float* out = (float*)d_out;
    // output layout (flat float offsets, return order)
    const long long O_CLU  = 4096000;     // cluster_out
    const long long O_FEAT = 8192000;     // cont_features
    const long long O_LAB  = 17629184;    // cont_labels
    const long long O_PROT = 17702912;    // new_prototypes
    const long long O_QUE  = 17830912;    // new_queue
    const long long O_QPS  = 26219520;    // new_queue_pseudo
    const long long O_PTR  = 26285056;    // new_ptr

    char* ws = (char*)d_ws;
    int*   lbl    = (int*)(ws + 0);                   // [4096]
    float* w      = (float*)(ws + 16384);             // [4096]
    int*   counts = (int*)(ws + 32768);               // [1024]
    float* scat   = (float*)(ws + 36864);             // [1000*128]
    __hip_bfloat16* qb = (__hip_bfloat16*)(ws + 1048576);  // [4096*128] bf16 (1 MB)
    __hip_bfloat16* pb = (__hip_bfloat16*)(ws + 2097152);  // [1024*128] bf16 (256 KB)

    // zero counts + scatter (contiguous)
    hipMemsetAsync(ws + 32768, 0, 4096 + 512000, stream);

    k_cls_softmax_argmax<<<Bn, 256, 0, stream>>>(cl, plab, out, lbl);
    k_convert<<<(Bn * Dn + CPAD * Dn + 255) / 256, 256, 0, stream>>>(q, proto, qb, pb);
    k_gemm_mfma<<<dim3(CPAD / 64, Bn / 64), 256, 0, stream>>>(qb, pb, out + O_CLU);
    k_softmax_inplace<<<Bn, 256, 0, stream>>>(out + O_CLU);
    k_rank<<<Bn / 4, 256, 0, stream>>>(lbl, w, counts);
    k_scatter<<<Bn, 128, 0, stream>>>(q, lbl, w, scat);
    k_proto<<<Cn, 128, 0, stream>>>(proto, scat, counts, out + O_PROT);
    k_copy<<<2048, 256, 0, stream>>>(q, kk, queue, ptrp, out + O_FEAT, out + O_QUE);
    k_labels<<<(2 * Bn + 2 * Qn + 1 + 255) / 256, 256, 0, stream>>>(
        lbl, qps, ptrp, out + O_LAB, out + O_QPS, out + O_PTR);
}

// Round 4
// 59.737 us; speedup vs baseline: 3.0637x; 1.2877x over previous
//
#include <hip/hip_runtime.h>
#include <hip/hip_bf16.h>
#include <math.h>

// Problem sizes
#define Bn 4096
#define Dn 128
#define Cn 1000
#define Qn 65536
#define CPAD 1024   // proto rows padded (zeros) so fragment loads are in-bounds

typedef __attribute__((ext_vector_type(8))) short short8v;  // bf16x8 MFMA frag
typedef __attribute__((ext_vector_type(4))) float f32x4;    // fp32x4 acc frag

__device__ inline float waveMaxF(float v) {
    for (int o = 32; o; o >>= 1) v = fmaxf(v, __shfl_down(v, o));
    return v;
}
__device__ inline float waveSumF(float v) {
    for (int o = 32; o; o >>= 1) v += __shfl_down(v, o);
    return v;
}

// ---------------- kernel 1: classfy softmax + masked argmax (+ bf16 convert fold) ----------------
__global__ __launch_bounds__(256) void k_cls_softmax_argmax(
    const float* __restrict__ logits, const float* __restrict__ plabel,
    const float* __restrict__ q, const float* __restrict__ proto,
    float* __restrict__ out, int* __restrict__ labels,
    __hip_bfloat16* __restrict__ qb, __hip_bfloat16* __restrict__ pb)
{
    __shared__ float sh[8];
    __shared__ int   shi[4];
    int row = blockIdx.x, t = threadIdx.x;

    // folded fp32->bf16 convert: 160 elems per block covers NQ+NP exactly
    {
        const int NQ = Bn * Dn;       // 524288
        const int NP = CPAD * Dn;     // 131072
        if (t < 160) {
            int i = row * 160 + t;
            if (i < NQ) qb[i] = __float2bfloat16(q[i]);
            else {
                int j = i - NQ;
                if (j < NP) pb[j] = __float2bfloat16(j < Cn * Dn ? proto[j] : 0.f);
            }
        }
    }

    const float* x = logits + (long long)row * Cn;
    float v[4];
    float mx = -INFINITY;
#pragma unroll
    for (int u = 0; u < 4; ++u) {
        int c = t + u * 256;
        v[u] = (c < Cn) ? x[c] : -INFINITY;
        mx = fmaxf(mx, v[u]);
    }
    int lane = t & 63, wid = t >> 6;
    mx = waveMaxF(mx);
    if (lane == 0) sh[wid] = mx;
    __syncthreads();
    if (t == 0) {
        float m = sh[0];
        for (int i = 1; i < 4; ++i) m = fmaxf(m, sh[i]);
        sh[4] = m;
    }
    __syncthreads();
    mx = sh[4];

    float s = 0.f;
#pragma unroll
    for (int u = 0; u < 4; ++u) {
        int c = t + u * 256;
        v[u] = (c < Cn) ? expf(v[u] - mx) : 0.f;
        s += v[u];
    }
    s = waveSumF(s);
    if (lane == 0) sh[wid] = s;
    __syncthreads();
    if (t == 0) {
        float ss = 0.f;
        for (int i = 0; i < 4; ++i) ss += sh[i];
        sh[5] = ss;
    }
    __syncthreads();
    s = sh[5];

    float bv = -INFINITY; int bi = Cn;
#pragma unroll
    for (int u = 0; u < 4; ++u) {
        int c = t + u * 256;
        if (c < Cn) {
            float o = v[u] / s;
            out[(long long)row * Cn + c] = o;
            float pr = o * plabel[(long long)row * Cn + c];
            if (pr > bv || (pr == bv && c < bi)) { bv = pr; bi = c; }
        }
    }
    for (int o = 32; o; o >>= 1) {
        float ov = __shfl_down(bv, o);
        int   oi = __shfl_down(bi, o);
        if (ov > bv || (ov == bv && oi < bi)) { bv = ov; bi = oi; }
    }
    __syncthreads();
    if (lane == 0) { sh[wid] = bv; shi[wid] = bi; }
    __syncthreads();
    if (t == 0) {
        float fb = sh[0]; int fi = shi[0];
        for (int i = 1; i < 4; ++i)
            if (sh[i] > fb || (sh[i] == fb && shi[i] < fi)) { fb = sh[i]; fi = shi[i]; }
        labels[row] = fi;
    }
}

// ---------------- kernel 2: fused cluster GEMM + row softmax ----------------
// 256 blocks x 16 rows. 4 waves; wave w owns cols [w*256, w*256+256).
// Each wave: 16 col-tiles of 16x16x32 MFMA, acc[j] over K=128.
// C/D layout (m89): col = lane&15, row = (lane>>4)*4 + reg.
// Row-softmax: shfl_xor reduce over la (16 cols), LDS reduce over j/waves.
__global__ __launch_bounds__(256) void k_gemm_softmax(
    const __hip_bfloat16* __restrict__ qb, const __hip_bfloat16* __restrict__ pb,
    float* __restrict__ outC)
{
    __shared__ float red[16][4];
    int t = threadIdx.x, lane = t & 63, w = t >> 6;
    int la = lane & 15, lk = lane >> 4;
    int row0 = blockIdx.x * 16;

    f32x4 acc[16];
#pragma unroll
    for (int j = 0; j < 16; ++j) acc[j] = (f32x4){0.f, 0.f, 0.f, 0.f};

    const short* A = (const short*)qb + (long long)(row0 + la) * Dn;
    const short* Bp = (const short*)pb;
#pragma unroll
    for (int kc = 0; kc < Dn; kc += 32) {
        short8v a = *(const short8v*)(A + kc + lk * 8);
#pragma unroll
        for (int j = 0; j < 16; ++j) {
            int prow = w * 256 + j * 16 + la;
            short8v b = *(const short8v*)(Bp + (long long)prow * Dn + kc + lk * 8);
            acc[j] = __builtin_amdgcn_mfma_f32_16x16x32_bf16(a, b, acc[j], 0, 0, 0);
        }
    }

    // --- row max (mask padded cols >= Cn) ---
    float m[4];
#pragma unroll
    for (int rg = 0; rg < 4; ++rg) {
        float v = -INFINITY;
#pragma unroll
        for (int j = 0; j < 16; ++j) {
            int col = w * 256 + j * 16 + la;
            if (col < Cn) v = fmaxf(v, acc[j][rg]);
        }
#pragma unroll
        for (int o = 1; o < 16; o <<= 1) v = fmaxf(v, __shfl_xor(v, o));
        m[rg] = v;
    }
    if (la == 0) {
#pragma unroll
        for (int rg = 0; rg < 4; ++rg) red[lk * 4 + rg][w] = m[rg];
    }
    __syncthreads();
#pragma unroll
    for (int rg = 0; rg < 4; ++rg) {
        int r = lk * 4 + rg;
        m[rg] = fmaxf(fmaxf(red[r][0], red[r][1]), fmaxf(red[r][2], red[r][3]));
    }
    __syncthreads();   // red reused for sums

    // --- exp + row sum ---
    float s[4];
#pragma unroll
    for (int rg = 0; rg < 4; ++rg) {
        float v = 0.f;
#pragma unroll
        for (int j = 0; j < 16; ++j) {
            int col = w * 256 + j * 16 + la;
            float e = (col < Cn) ? expf(acc[j][rg] - m[rg]) : 0.f;
            acc[j][rg] = e;
            v += e;
        }
#pragma unroll
        for (int o = 1; o < 16; o <<= 1) v += __shfl_xor(v, o);
        s[rg] = v;
    }
    if (la == 0) {
#pragma unroll
        for (int rg = 0; rg < 4; ++rg) red[lk * 4 + rg][w] = s[rg];
    }
    __syncthreads();
#pragma unroll
    for (int rg = 0; rg < 4; ++rg) {
        int r = lk * 4 + rg;
        s[rg] = 1.f / (red[r][0] + red[r][1] + red[r][2] + red[r][3]);
    }

    // --- write normalized probs ---
#pragma unroll
    for (int j = 0; j < 16; ++j) {
        int col = w * 256 + j * 16 + la;
        if (col < Cn) {
            int rowb = row0 + lk * 4;
#pragma unroll
            for (int rg = 0; rg < 4; ++rg)
                outC[(long long)(rowb + rg) * Cn + col] = acc[j][rg] * s[rg];
        }
    }
}

// ---------------- kernel 3: fused prototype EMA update + L2 norm ----------------
// Block c: stage labels in LDS, wave-0 ballot builds ORDERED match list,
// then 128 threads apply the exact sequential EMA and L2-normalize.
__global__ __launch_bounds__(128) void k_proto_fused(
    const float* __restrict__ proto, const float* __restrict__ q,
    const int* __restrict__ labels, float* __restrict__ outp)
{
    __shared__ int sl[Bn];
    __shared__ unsigned short list[Bn];
    __shared__ int nmatch;
    __shared__ float sh[2];
    int c = blockIdx.x, t = threadIdx.x;

#pragma unroll
    for (int u = 0; u < 8; ++u) {
        int base = (u * 128 + t) * 4;
        *(int4*)(sl + base) = *(const int4*)(labels + base);
    }
    if (t == 0) nmatch = 0;
    __syncthreads();

    if (t < 64) {
        for (int jj = 0; jj < Bn / 64; ++jj) {
            unsigned long long mask = __ballot(sl[jj * 64 + t] == c);
            if (t == 0 && mask) {
                int n = nmatch;
                while (mask) {
                    int b = __builtin_ctzll(mask);
                    list[n++] = (unsigned short)(jj * 64 + b);
                    mask &= mask - 1;
                }
                nmatch = n;
            }
        }
    }
    __syncthreads();

    int n = nmatch;
    float acc = proto[(long long)c * Dn + t];
    for (int mi = 0; mi < n; ++mi)
        acc = 0.99f * acc + 0.01f * q[(long long)list[mi] * Dn + t];

    float ss = waveSumF(acc * acc);
    if ((t & 63) == 0) sh[t >> 6] = ss;
    __syncthreads();
    float nn = sqrtf(sh[0] + sh[1]);
    outp[(long long)c * Dn + t] = acc / fmaxf(nn, 1e-12f);
}

// ---------------- kernel 4: fused copies + labels/ptr tail ----------------
__global__ void k_copy(const float* __restrict__ q, const float* __restrict__ kk,
                       const float* __restrict__ queue, const float* __restrict__ qps,
                       const int* __restrict__ lbl, const int* __restrict__ ptrp,
                       float* __restrict__ out_feat, float* __restrict__ out_queue,
                       float* __restrict__ out_lab, float* __restrict__ out_qps,
                       float* __restrict__ out_ptr)
{
    int p = *ptrp;
    int pc = p < 0 ? 0 : (p > Qn - Bn ? Qn - Bn : p);   // dynamic_update_slice clamp
    const long long QD = (long long)Bn * Dn;                  // 524288
    const long long n4 = (2 * QD + (long long)Qn * Dn) / 4;   // 2359296
    long long stride = (long long)gridDim.x * blockDim.x;
    for (long long i = (long long)blockIdx.x * blockDim.x + threadIdx.x; i < n4; i += stride) {
        long long off = i * 4;
        if (off < QD) {
            *(float4*)(out_feat + off) = *(const float4*)(q + off);
        } else if (off < 2 * QD) {
            *(float4*)(out_feat + off) = *(const float4*)(kk + off - QD);
        } else {
            long long qoff = off - 2 * QD;
            float4 v = *(const float4*)(queue + qoff);
            *(float4*)(out_feat + off) = v;
            int row = (int)(qoff >> 7);
            int col = (int)(qoff & 127);
            unsigned rr = (unsigned)(row - pc);
            if (rr < (unsigned)Bn) v = *(const float4*)(kk + (long long)rr * Dn + col);
            *(float4*)(out_queue + qoff) = v;
        }
    }
    // tail: cont_labels, new_queue_pseudo, new_ptr (139265 elems < grid threads)
    long long gid = (long long)blockIdx.x * blockDim.x + threadIdx.x;
    const int NL = 2 * Bn + Qn;   // 73728
    if (gid <= (long long)NL + Qn) {
        int i = (int)gid;
        if (i < NL) {
            float v;
            if (i < Bn)          v = (float)lbl[i];
            else if (i < 2 * Bn) v = (float)lbl[i - Bn];
            else                 v = qps[i - 2 * Bn];
            out_lab[i] = v;
        }
        int j = i - NL;
        if (j >= 0 && j < Qn) {
            unsigned rr = (unsigned)(j - pc);
            out_qps[j] = (rr < (unsigned)Bn) ? (float)lbl[rr] : qps[j];
        }
        if (i == NL + Qn) out_ptr[0] = (float)((p + Bn) % Qn);
    }
}

// ---------------- host ----------------
extern "C" void kernel_launch(void* const* d_in, const int* in_sizes, int n_in,
                              void* d_out, int out_size, void* d_ws, size_t ws_size,
                              hipStream_t stream)
{
    const float* q     = (const float*)d_in[0];
    const float* kk    = (const float*)d_in[1];
    const float* cl    = (const float*)d_in[2];
    const float* plab  = (const float*)d_in[3];
    const float* proto = (const float*)d_in[4];
    const float* queue = (const float*)d_in[5];
    const float* qps   = (const float*)d_in[6];
    const int*   ptrp  = (const int*)d_in[7];

    float* out = (float*)d_out;
    // output layout (flat float offsets, return order)
    const long long O_CLU  = 4096000;     // cluster_out
    const long long O_FEAT = 8192000;     // cont_features
    const long long O_LAB  = 17629184;    // cont_labels
    const long long O_PROT = 17702912;    // new_prototypes
    const long long O_QUE  = 17830912;    // new_queue
    const long long O_QPS  = 26219520;    // new_queue_pseudo
    const long long O_PTR  = 26285056;    // new_ptr

    char* ws = (char*)d_ws;
    int*   lbl = (int*)(ws + 0);                           // [4096]
    __hip_bfloat16* qb = (__hip_bfloat16*)(ws + 1048576);  // [4096*128] bf16
    __hip_bfloat16* pb = (__hip_bfloat16*)(ws + 2097152);  // [1024*128] bf16 (padded)

    k_cls_softmax_argmax<<<Bn, 256, 0, stream>>>(cl, plab, q, proto, out, lbl, qb, pb);
    k_gemm_softmax<<<Bn / 16, 256, 0, stream>>>(qb, pb, out + O_CLU);
    k_proto_fused<<<Cn, 128, 0, stream>>>(proto, q, lbl, out + O_PROT);
    k_copy<<<2048, 256, 0, stream>>>(q, kk, queue, qps, lbl, ptrp,
                                     out + O_FEAT, out + O_QUE,
                                     out + O_LAB, out + O_QPS, out + O_PTR);
}

// Round 5
// 49.417 us; speedup vs baseline: 3.7034x; 1.2088x over previous
//
#include <hip/hip_runtime.h>
#include <hip/hip_bf16.h>
#include <math.h>

// Problem sizes
#define Bn 4096
#define Dn 128
#define Cn 1000
#define Qn 65536
#define CPAD 1024   // proto rows padded (zeros) so fragment loads are in-bounds

typedef __attribute__((ext_vector_type(8))) short short8v;  // bf16x8 MFMA frag
typedef __attribute__((ext_vector_type(4))) float f32x4;    // fp32x4 acc frag

__device__ inline float waveMaxF(float v) {
    for (int o = 32; o; o >>= 1) v = fmaxf(v, __shfl_down(v, o));
    return v;
}
__device__ inline float waveSumF(float v) {
    for (int o = 32; o; o >>= 1) v += __shfl_down(v, o);
    return v;
}

// ================= PHASE 1 =================
// 6144 blocks, roles interleaved 2 cls : 1 copy so HBM stays saturated.
//   bid%3==2 -> copy block (cidx = bid/3, 2048 total): cont_features + new_queue
//   else     -> cls block (row = (bid/3)*2 + bid%3, 4096 total):
//              classfy softmax + masked argmax + bf16-convert fold
__global__ __launch_bounds__(256) void k_phase1(
    const float* __restrict__ logits, const float* __restrict__ plabel,
    const float* __restrict__ q, const float* __restrict__ proto,
    const float* __restrict__ kk, const float* __restrict__ queue,
    const int* __restrict__ ptrp,
    float* __restrict__ out_cls, int* __restrict__ labels,
    __hip_bfloat16* __restrict__ qb, __hip_bfloat16* __restrict__ pb,
    float* __restrict__ out_feat, float* __restrict__ out_queue)
{
    int bid = blockIdx.x, t = threadIdx.x;
    int r3 = bid % 3;

    if (r3 == 2) {
        // ---- copy block ----
        int cidx = bid / 3;
        int p = *ptrp;
        int pc = p < 0 ? 0 : (p > Qn - Bn ? Qn - Bn : p);   // dynamic_update_slice clamp
        const long long QD = (long long)Bn * Dn;                  // 524288
        const long long n4 = (2 * QD + (long long)Qn * Dn) / 4;   // 2359296
        const long long stride = 2048LL * 256;
        for (long long i = (long long)cidx * 256 + t; i < n4; i += stride) {
            long long off = i * 4;
            if (off < QD) {
                *(float4*)(out_feat + off) = *(const float4*)(q + off);
            } else if (off < 2 * QD) {
                *(float4*)(out_feat + off) = *(const float4*)(kk + off - QD);
            } else {
                long long qoff = off - 2 * QD;
                float4 v = *(const float4*)(queue + qoff);
                *(float4*)(out_feat + off) = v;
                int row = (int)(qoff >> 7);
                int col = (int)(qoff & 127);
                unsigned rr = (unsigned)(row - pc);
                if (rr < (unsigned)Bn) v = *(const float4*)(kk + (long long)rr * Dn + col);
                *(float4*)(out_queue + qoff) = v;
            }
        }
        return;
    }

    // ---- cls block ----
    int row = (bid / 3) * 2 + r3;
    __shared__ float sh[8];
    __shared__ int   shi[4];

    // folded fp32->bf16 convert: 160 elems per cls block covers NQ+NP exactly
    {
        const int NQ = Bn * Dn;       // 524288
        const int NP = CPAD * Dn;     // 131072
        if (t < 160) {
            int i = row * 160 + t;
            if (i < NQ) qb[i] = __float2bfloat16(q[i]);
            else {
                int j = i - NQ;
                if (j < NP) pb[j] = __float2bfloat16(j < Cn * Dn ? proto[j] : 0.f);
            }
        }
    }

    bool act = t < 250;                 // 250 float4 = 1000 floats exactly
    float vv[4];
    if (act) {
        float4 v4 = ((const float4*)(logits + (long long)row * Cn))[t];
        vv[0] = v4.x; vv[1] = v4.y; vv[2] = v4.z; vv[3] = v4.w;
    } else {
        vv[0] = vv[1] = vv[2] = vv[3] = -INFINITY;
    }
    int lane = t & 63, wid = t >> 6;

    float mx = fmaxf(fmaxf(vv[0], vv[1]), fmaxf(vv[2], vv[3]));
    mx = waveMaxF(mx);
    if (lane == 0) sh[wid] = mx;
    __syncthreads();
    if (t == 0) {
        float m = sh[0];
        for (int i = 1; i < 4; ++i) m = fmaxf(m, sh[i]);
        sh[4] = m;
    }
    __syncthreads();
    mx = sh[4];

    float s = 0.f;
#pragma unroll
    for (int j = 0; j < 4; ++j) {
        vv[j] = act ? expf(vv[j] - mx) : 0.f;
        s += vv[j];
    }
    s = waveSumF(s);
    if (lane == 0) sh[wid] = s;
    __syncthreads();
    if (t == 0) {
        float ss = 0.f;
        for (int i = 0; i < 4; ++i) ss += sh[i];
        sh[5] = ss;
    }
    __syncthreads();
    float inv = 1.f / sh[5];

    float bv = -INFINITY; int bi = Cn;
    if (act) {
        float4 p4 = ((const float4*)(plabel + (long long)row * Cn))[t];
        float o0 = vv[0] * inv, o1 = vv[1] * inv, o2 = vv[2] * inv, o3 = vv[3] * inv;
        ((float4*)(out_cls + (long long)row * Cn))[t] = make_float4(o0, o1, o2, o3);
        float pr[4] = {o0 * p4.x, o1 * p4.y, o2 * p4.z, o3 * p4.w};
#pragma unroll
        for (int j = 0; j < 4; ++j) {       // ascending j: strict > keeps first max
            if (pr[j] > bv) { bv = pr[j]; bi = t * 4 + j; }
        }
    }
    for (int o = 32; o; o >>= 1) {
        float ov = __shfl_down(bv, o);
        int   oi = __shfl_down(bi, o);
        if (ov > bv || (ov == bv && oi < bi)) { bv = ov; bi = oi; }
    }
    __syncthreads();
    if (lane == 0) { sh[wid] = bv; shi[wid] = bi; }
    __syncthreads();
    if (t == 0) {
        float fb = sh[0]; int fi = shi[0];
        for (int i = 1; i < 4; ++i)
            if (sh[i] > fb || (sh[i] == fb && shi[i] < fi)) { fb = sh[i]; fi = shi[i]; }
        labels[row] = fi;
    }
}

// ================= PHASE 2 =================
// 1301 blocks:
//   bid <  256 : cluster GEMM + row softmax (16 rows/block)
//   bid <  756 : prototype EMA + L2 norm (2 classes/block)
//   else       : cont_labels / new_queue_pseudo / new_ptr tail
__global__ __launch_bounds__(256) void k_phase2(
    const __hip_bfloat16* __restrict__ qb, const __hip_bfloat16* __restrict__ pb,
    const float* __restrict__ proto, const float* __restrict__ q,
    const int* __restrict__ lbl, const float* __restrict__ qps,
    const int* __restrict__ ptrp,
    float* __restrict__ outC, float* __restrict__ outp,
    float* __restrict__ out_lab, float* __restrict__ out_qps,
    float* __restrict__ out_ptr)
{
    __shared__ __align__(16) char smem[32800];
    int bid = blockIdx.x, t = threadIdx.x;

    if (bid < 256) {
        // ---- GEMM + softmax ----
        float (*red)[4] = (float (*)[4])smem;   // [16][4]
        int lane = t & 63, w = t >> 6;
        int la = lane & 15, lk = lane >> 4;
        int row0 = bid * 16;

        f32x4 acc[16];
#pragma unroll
        for (int j = 0; j < 16; ++j) acc[j] = (f32x4){0.f, 0.f, 0.f, 0.f};

        const short* A = (const short*)qb + (long long)(row0 + la) * Dn;
        const short* Bp = (const short*)pb;
#pragma unroll
        for (int kc = 0; kc < Dn; kc += 32) {
            short8v a = *(const short8v*)(A + kc + lk * 8);
#pragma unroll
            for (int j = 0; j < 16; ++j) {
                int prow = w * 256 + j * 16 + la;
                short8v b = *(const short8v*)(Bp + (long long)prow * Dn + kc + lk * 8);
                acc[j] = __builtin_amdgcn_mfma_f32_16x16x32_bf16(a, b, acc[j], 0, 0, 0);
            }
        }

        float m[4];
#pragma unroll
        for (int rg = 0; rg < 4; ++rg) {
            float v = -INFINITY;
#pragma unroll
            for (int j = 0; j < 16; ++j) {
                int col = w * 256 + j * 16 + la;
                if (col < Cn) v = fmaxf(v, acc[j][rg]);
            }
#pragma unroll
            for (int o = 1; o < 16; o <<= 1) v = fmaxf(v, __shfl_xor(v, o));
            m[rg] = v;
        }
        if (la == 0) {
#pragma unroll
            for (int rg = 0; rg < 4; ++rg) red[lk * 4 + rg][w] = m[rg];
        }
        __syncthreads();
#pragma unroll
        for (int rg = 0; rg < 4; ++rg) {
            int r = lk * 4 + rg;
            m[rg] = fmaxf(fmaxf(red[r][0], red[r][1]), fmaxf(red[r][2], red[r][3]));
        }
        __syncthreads();

        float s[4];
#pragma unroll
        for (int rg = 0; rg < 4; ++rg) {
            float v = 0.f;
#pragma unroll
            for (int j = 0; j < 16; ++j) {
                int col = w * 256 + j * 16 + la;
                float e = (col < Cn) ? expf(acc[j][rg] - m[rg]) : 0.f;
                acc[j][rg] = e;
                v += e;
            }
#pragma unroll
            for (int o = 1; o < 16; o <<= 1) v += __shfl_xor(v, o);
            s[rg] = v;
        }
        if (la == 0) {
#pragma unroll
            for (int rg = 0; rg < 4; ++rg) red[lk * 4 + rg][w] = s[rg];
        }
        __syncthreads();
#pragma unroll
        for (int rg = 0; rg < 4; ++rg) {
            int r = lk * 4 + rg;
            s[rg] = 1.f / (red[r][0] + red[r][1] + red[r][2] + red[r][3]);
        }

#pragma unroll
        for (int j = 0; j < 16; ++j) {
            int col = w * 256 + j * 16 + la;
            if (col < Cn) {
                int rowb = row0 + lk * 4;
#pragma unroll
                for (int rg = 0; rg < 4; ++rg)
                    outC[(long long)(rowb + rg) * Cn + col] = acc[j][rg] * s[rg];
            }
        }
    } else if (bid < 756) {
        // ---- prototype EMA + L2 norm, 2 classes per block ----
        int* sl = (int*)smem;                                   // [4096]
        unsigned short* list0 = (unsigned short*)(smem + 16384); // [4096]
        unsigned short* list1 = list0 + 4096;                    // [4096]
        int* nm = (int*)(smem + 32768);                          // [2]
        float* shh = (float*)(smem + 32776);                     // [4]

        int h = t >> 7, tt = t & 127;
        int c = (bid - 256) * 2 + h;                             // < 1000 always

#pragma unroll
        for (int u = 0; u < 4; ++u) {
            int base = (u * 256 + t) * 4;
            *(int4*)(sl + base) = *(const int4*)(lbl + base);
        }
        if (t == 0)   nm[0] = 0;
        if (t == 128) nm[1] = 0;
        __syncthreads();

        int wv = t >> 6;
        if ((wv & 1) == 0) {            // waves 0 and 2 scan for their half's class
            int hh = wv >> 1;
            int ln = t & 63;
            int cc = (bid - 256) * 2 + hh;
            unsigned short* lst = hh ? list1 : list0;
            int n = 0;
            for (int jj = 0; jj < Bn / 64; ++jj) {
                unsigned long long mask = __ballot(sl[jj * 64 + ln] == cc);
                if (ln == 0) {
                    while (mask) {
                        int b = __builtin_ctzll(mask);
                        lst[n++] = (unsigned short)(jj * 64 + b);
                        mask &= mask - 1;
                    }
                }
            }
            if (ln == 0) nm[hh] = n;
        }
        __syncthreads();

        int n = nm[h];
        unsigned short* lst = h ? list1 : list0;
        float acc = proto[(long long)c * Dn + tt];
        for (int mi = 0; mi < n; ++mi)
            acc = 0.99f * acc + 0.01f * q[(long long)lst[mi] * Dn + tt];

        float ss = waveSumF(acc * acc);
        if ((t & 63) == 0) shh[t >> 6] = ss;
        __syncthreads();
        float nn = sqrtf(shh[h * 2] + shh[h * 2 + 1]);
        outp[(long long)c * Dn + tt] = acc / fmaxf(nn, 1e-12f);
    } else {
        // ---- labels / queue_pseudo / ptr tail ----
        int gid = (bid - 756) * 256 + t;
        const int NL = 2 * Bn + Qn;   // 73728
        int p = *ptrp;
        int pc = p < 0 ? 0 : (p > Qn - Bn ? Qn - Bn : p);
        if (gid < NL) {
            float v;
            if (gid < Bn)          v = (float)lbl[gid];
            else if (gid < 2 * Bn) v = (float)lbl[gid - Bn];
            else                   v = qps[gid - 2 * Bn];
            out_lab[gid] = v;
        }
        int j = gid - NL;
        if (j >= 0 && j < Qn) {
            unsigned rr = (unsigned)(j - pc);
            out_qps[j] = (rr < (unsigned)Bn) ? (float)lbl[rr] : qps[j];
        }
        if (gid == NL + Qn) out_ptr[0] = (float)((p + Bn) % Qn);
    }
}

// ---------------- host ----------------
extern "C" void kernel_launch(void* const* d_in, const int* in_sizes, int n_in,
                              void* d_out, int out_size, void* d_ws, size_t ws_size,
                              hipStream_t stream)
{
    const float* q     = (const float*)d_in[0];
    const float* kk    = (const float*)d_in[1];
    const float* cl    = (const float*)d_in[2];
    const float* plab  = (const float*)d_in[3];
    const float* proto = (const float*)d_in[4];
    const float* queue = (const float*)d_in[5];
    const float* qps   = (const float*)d_in[6];
    const int*   ptrp  = (const int*)d_in[7];

    float* out = (float*)d_out;
    // output layout (flat float offsets, return order)
    const long long O_CLU  = 4096000;     // cluster_out
    const long long O_FEAT = 8192000;     // cont_features
    const long long O_LAB  = 17629184;    // cont_labels
    const long long O_PROT = 17702912;    // new_prototypes
    const long long O_QUE  = 17830912;    // new_queue
    const long long O_QPS  = 26219520;    // new_queue_pseudo
    const long long O_PTR  = 26285056;    // new_ptr

    char* ws = (char*)d_ws;
    int*   lbl = (int*)(ws + 0);                           // [4096]
    __hip_bfloat16* qb = (__hip_bfloat16*)(ws + 1048576);  // [4096*128] bf16
    __hip_bfloat16* pb = (__hip_bfloat16*)(ws + 2097152);  // [1024*128] bf16 (padded)

    k_phase1<<<6144, 256, 0, stream>>>(cl, plab, q, proto, kk, queue, ptrp,
                                       out, lbl, qb, pb, out + O_FEAT, out + O_QUE);
    k_phase2<<<1301, 256, 0, stream>>>(qb, pb, proto, q, lbl, qps, ptrp,
                                       out + O_CLU, out + O_PROT,
                                       out + O_LAB, out + O_QPS, out + O_PTR);
}